// Round 3
// baseline (115.778 us; speedup 1.0000x reference)
//
#include <hip/hip_runtime.h>

// GauntTensorProductFixedParity — R9: fused, zero-transpose MFMA chain.
//
// Algebraic restructure vs R8: stage 1 computes c^T = W^T·in^T (operands
// swapped), so its C-layout (n=row=lo16, k=s=quad*4+i) IS the B-operand
// layout of the K=16 MFMA — the same chain trick GEMM2 already uses.
// The per-wave LDS scratch transpose is gone; LDS holds only Y/Yw frags.
//
//   stage 1 (16x16x32): c^T[s,row]  = sum_d W[d,s]·in[row,d]     (A=W, B=in)
//   stage 2 (16x16x16): G[p,row]    = sum_s Y[p,s]·c^T[s,row]    (A=Yf, B=c-chain, acc over 2 s-halves)
//   H = G1 ⊙ G2 (f32->f16 in regs)
//   GEMM2   (16x16x16): out[s,row] += sum_p Yw^T[s,p]·H[p,row]   (A=Ywf, B=H-chain)
//
// Verified lane mappings (R7/R8 lineage):
//   A/B-frag K=32: (idx = lane&15, k = quad*8+j)
//   A/B-frag K=16: (idx = lane&15, k = quad*4+i)
//   C/D:           (n = lane&15,   m = quad*4+i)
// Input global loads are issued FIRST; Y/Yw->LDS staging overlaps their
// HBM latency; one barrier; then the whole chain is register-resident.
//
// LDS: Yf [pt9][st2][64][4]h = 9216B | Ywf [st2][pt9][64][4]h = 9216B.
// Grid 512 x 256 thr, 256 rows/block, 4 waves x 4 row-tiles (64 rows/wave).

typedef _Float16 f16x8 __attribute__((ext_vector_type(8)));
typedef _Float16 f16x4 __attribute__((ext_vector_type(4)));
typedef float f32x4 __attribute__((ext_vector_type(4)));
typedef float f32x4u __attribute__((ext_vector_type(4), aligned(4)));

namespace {
constexpr int kD = 64, kS = 25, kP = 132;
constexpr int kBlock = 256, kM = 256;        // rows per block (4 waves x 64 rows)
constexpr int kYfOff = 0;                    // [9][2][64][4] halfs = 4608
constexpr int kYwOff = 4608;                 // [2][9][64][4] halfs = 4608
constexpr int kLdsHalfs = 9216;              // 18432 B
}

__device__ __forceinline__ f16x4 ld4(const _Float16* p) {
    return *reinterpret_cast<const f16x4*>(p);
}
__device__ __forceinline__ f16x8 cvt8h(f32x4 u, f32x4 v) {
    f16x8 r;
    r[0] = (_Float16)u[0]; r[1] = (_Float16)u[1];
    r[2] = (_Float16)u[2]; r[3] = (_Float16)u[3];
    r[4] = (_Float16)v[0]; r[5] = (_Float16)v[1];
    r[6] = (_Float16)v[2]; r[7] = (_Float16)v[3];
    return r;
}

__global__ __launch_bounds__(kBlock, 2) void gaunt_fused9(
    const float* __restrict__ in1, const float* __restrict__ in2,
    const float* __restrict__ W1, const float* __restrict__ W2,
    const float* __restrict__ Y,  const float* __restrict__ Yw,
    float* __restrict__ out)
{
    __shared__ _Float16 lds[kLdsHalfs];
    const int tid  = threadIdx.x;
    const int lane = tid & 63;
    const int w    = __builtin_amdgcn_readfirstlane(tid >> 6);
    const int lo16 = lane & 15, quad = lane >> 4;

    // ---- Phase A (FIRST): issue the input HBM burst. B-frag (n=row, k=d). ----
    const long long base = (long long)blockIdx.x * (kM * kD);
    f32x4 u1[4][2], v1[4][2], u2[4][2], v2[4][2];
    #pragma unroll
    for (int rt = 0; rt < 4; ++rt) {
        const int row = (4 * w + rt) * 16 + lo16;
        const float* p1 = in1 + base + row * kD + quad * 8;
        const float* p2 = in2 + base + row * kD + quad * 8;
        #pragma unroll
        for (int ks = 0; ks < 2; ++ks) {
            u1[rt][ks] = *reinterpret_cast<const f32x4*>(p1 + ks * 32);
            v1[rt][ks] = *reinterpret_cast<const f32x4*>(p1 + ks * 32 + 4);
            u2[rt][ks] = *reinterpret_cast<const f32x4*>(p2 + ks * 32);
            v2[rt][ks] = *reinterpret_cast<const f32x4*>(p2 + ks * 32 + 4);
        }
    }

    // ---- Phase B: Y K=16 A-frags -> LDS (overlaps input latency).
    //      Yf(pt,st): A(m = p = pt*16+lo16, k = s = st*16+quad*4+i)
    for (int e = tid; e < 4608; e += kBlock) {
        const int i = e & 3, ln = (e >> 2) & 63, r = e >> 8;  // r 0..17
        const int pt = r >> 1, st = r & 1;
        const int p = pt * 16 + (ln & 15);                    // 0..143
        const int s = st * 16 + ((ln >> 4) & 3) * 4 + i;      // 0..31
        lds[kYfOff + e] = (s < kS && p < kP) ? (_Float16)Y[p * kS + s]
                                             : (_Float16)0.f;
    }
    // ---- Ywt K=16 A-frags -> LDS.  A(m = s = st*16+lo16, k = p = pt*16+quad*4+i)
    for (int e = tid; e < 4608; e += kBlock) {
        const int i = e & 3, ln = (e >> 2) & 63, r = e >> 8;  // r 0..17
        const int pt = r % 9, st = r / 9;
        const int p = pt * 16 + ((ln >> 4) & 3) * 4 + i;      // 0..143
        const int s = st * 16 + (ln & 15);                    // 0..31
        lds[kYwOff + e] = (s < kS && p < kP) ? (_Float16)Yw[p * kS + s]
                                             : (_Float16)0.f;
    }

    // ---- Phase C: W A-frags (K=32) -> registers.  A(m = s, k = d) = W[d][s]
    f16x8 w1f[2][2], w2f[2][2];                   // [st][ks]
    #pragma unroll
    for (int st = 0; st < 2; ++st) {
        const int s = st * 16 + lo16;
        #pragma unroll
        for (int ks = 0; ks < 2; ++ks) {
            f16x8 a, b;
            #pragma unroll
            for (int j = 0; j < 8; ++j) { a[j] = (_Float16)0.f; b[j] = (_Float16)0.f; }
            if (s < kS) {
                const int d0 = ks * 32 + quad * 8;
                #pragma unroll
                for (int j = 0; j < 8; ++j) {
                    a[j] = (_Float16)W1[(d0 + j) * kS + s];
                    b[j] = (_Float16)W2[(d0 + j) * kS + s];
                }
            }
            w1f[st][ks] = a; w2f[st][ks] = b;
        }
    }

    __syncthreads();

    // ---- cvt inputs to f16 B-frags ----
    f16x8 b1[4][2], b2[4][2];
    #pragma unroll
    for (int rt = 0; rt < 4; ++rt)
        #pragma unroll
        for (int ks = 0; ks < 2; ++ks) {
            b1[rt][ks] = cvt8h(u1[rt][ks], v1[rt][ks]);
            b2[rt][ks] = cvt8h(u2[rt][ks], v2[rt][ks]);
        }

    // ---- Stage 1: c^T = W^T·in^T.  C(n=row=lo16, m=s=quad*4+i) -> f16 chain frags
    f16x4 h1c[4][2], h2c[4][2];                   // [rt][st] B-frags (n=row, k=s)
    #pragma unroll
    for (int rt = 0; rt < 4; ++rt) {
        #pragma unroll
        for (int st = 0; st < 2; ++st) {
            f32x4 c1 = (f32x4){0.f, 0.f, 0.f, 0.f};
            f32x4 c2 = (f32x4){0.f, 0.f, 0.f, 0.f};
            #pragma unroll
            for (int ks = 0; ks < 2; ++ks) {
                c1 = __builtin_amdgcn_mfma_f32_16x16x32_f16(w1f[st][ks], b1[rt][ks], c1, 0, 0, 0);
                c2 = __builtin_amdgcn_mfma_f32_16x16x32_f16(w2f[st][ks], b2[rt][ks], c2, 0, 0, 0);
            }
            f16x4 hc1, hc2;
            #pragma unroll
            for (int i = 0; i < 4; ++i) {
                hc1[i] = (_Float16)c1[i];
                hc2[i] = (_Float16)c2[i];
            }
            h1c[rt][st] = hc1; h2c[rt][st] = hc2;
        }
    }

    // ---- Stage 2 + GEMM2 over 9 p-tiles; Y/Yw frags double-buffered from LDS
    f32x4 oacc[4][2];
    #pragma unroll
    for (int rt = 0; rt < 4; ++rt)
        #pragma unroll
        for (int st = 0; st < 2; ++st)
            oacc[rt][st] = (f32x4){0.f, 0.f, 0.f, 0.f};

    f16x4 yfc[2], yw0c, yw1c;
    yfc[0] = ld4(&lds[kYfOff + (0 * 2 + 0) * 256 + lane * 4]);
    yfc[1] = ld4(&lds[kYfOff + (0 * 2 + 1) * 256 + lane * 4]);
    yw0c   = ld4(&lds[kYwOff + (0 * 9 + 0) * 256 + lane * 4]);
    yw1c   = ld4(&lds[kYwOff + (1 * 9 + 0) * 256 + lane * 4]);

    #pragma unroll 1
    for (int pt = 0; pt < 9; ++pt) {
        f16x4 yfn[2], yw0n, yw1n;
        if (pt < 8) {
            yfn[0] = ld4(&lds[kYfOff + ((pt + 1) * 2 + 0) * 256 + lane * 4]);
            yfn[1] = ld4(&lds[kYfOff + ((pt + 1) * 2 + 1) * 256 + lane * 4]);
            yw0n   = ld4(&lds[kYwOff + (0 * 9 + pt + 1) * 256 + lane * 4]);
            yw1n   = ld4(&lds[kYwOff + (1 * 9 + pt + 1) * 256 + lane * 4]);
        }
        #pragma unroll
        for (int rt = 0; rt < 4; ++rt) {
            const f32x4 z = (f32x4){0.f, 0.f, 0.f, 0.f};
            f32x4 g1 = __builtin_amdgcn_mfma_f32_16x16x16f16(yfc[0], h1c[rt][0], z, 0, 0, 0);
            g1       = __builtin_amdgcn_mfma_f32_16x16x16f16(yfc[1], h1c[rt][1], g1, 0, 0, 0);
            f32x4 g2 = __builtin_amdgcn_mfma_f32_16x16x16f16(yfc[0], h2c[rt][0], z, 0, 0, 0);
            g2       = __builtin_amdgcn_mfma_f32_16x16x16f16(yfc[1], h2c[rt][1], g2, 0, 0, 0);
            f16x4 h;
            h[0] = (_Float16)(g1[0] * g2[0]);
            h[1] = (_Float16)(g1[1] * g2[1]);
            h[2] = (_Float16)(g1[2] * g2[2]);
            h[3] = (_Float16)(g1[3] * g2[3]);
            oacc[rt][0] = __builtin_amdgcn_mfma_f32_16x16x16f16(yw0c, h, oacc[rt][0], 0, 0, 0);
            oacc[rt][1] = __builtin_amdgcn_mfma_f32_16x16x16f16(yw1c, h, oacc[rt][1], 0, 0, 0);
        }
        yfc[0] = yfn[0]; yfc[1] = yfn[1]; yw0c = yw0n; yw1c = yw1n;
    }

    // ---- stores: out^T C-layout (n=row=lo16, m=s=quad*4+i) -> 16B runs ----
    const long long ob = (long long)blockIdx.x * (kM * kS);
    #pragma unroll
    for (int rt = 0; rt < 4; ++rt) {
        const int row = (4 * w + rt) * 16 + lo16;
        float* rp = out + ob + (long long)row * kS;
        // st=0: s = quad*4 + i, 0..15 all valid
        *reinterpret_cast<f32x4u*>(rp + quad * 4) = oacc[rt][0];
        // st=1: s = 16 + quad*4 + i, valid while < 25
        if (quad < 2) {
            *reinterpret_cast<f32x4u*>(rp + 16 + quad * 4) = oacc[rt][1];
        } else if (quad == 2) {
            rp[24] = oacc[rt][1][0];
        }
    }
}

extern "C" void kernel_launch(void* const* d_in, const int* in_sizes, int n_in,
                              void* d_out, int out_size, void* d_ws, size_t ws_size,
                              hipStream_t stream) {
    const float* in1 = (const float*)d_in[0];   // [N, 64]
    const float* in2 = (const float*)d_in[1];   // [N, 64]
    const float* W1  = (const float*)d_in[2];   // [64, 25]
    const float* W2  = (const float*)d_in[3];   // [64, 25]
    const float* Y   = (const float*)d_in[4];   // [132, 25]
    const float* Yw  = (const float*)d_in[5];   // [132, 25]
    float* out = (float*)d_out;                 // [N, 25]
    (void)d_ws; (void)ws_size;

    const int n_rows = in_sizes[0] / kD;        // 131072
    const int grid = n_rows / kM;               // 512
    gaunt_fused9<<<grid, kBlock, 0, stream>>>(in1, in2, W1, W2, Y, Yw, out);
}